// Round 6
// baseline (53.498 us; speedup 1.0000x reference)
//
#include <hip/hip_runtime.h>

// Problem: out[r][c] = in[r][c] * weight[c][c] + bias[c]
// B = 8192 rows, N = 4096 cols, all float32.
// Pure memory-bound: 128 MiB read + 128 MiB write. Copy-roofline ~43 us.
//
// Lessons:
//  - R3: __builtin_nontemporal_* regressed (69.5 us) — bypasses L2
//    aggregation on gfx950; stay on cached path.
//  - R4: 16x unroll regressed (56.7 us) — long vmcnt batches kill
//    request overlap; keep the streaming loop ROLLED.
//  - R5: fused strided diag prologue regressed (53.1 us vs R1 50.7) —
//    4 loads/thread at 16 KiB stride fragment into ~256 txns/wave at
//    kernel start. Diagonal must be read COALESCED from a ws copy.
//  - This round: R1's ws-diag (coalesced) + R5's register hoisting
//    (j = t & 1023 invariant under grid stride 524288) + rolled loop.

#define NCOL 4096
#define NROW 8192
#define QCOL (NCOL / 4)   // 1024 column quads

typedef float f4 __attribute__((ext_vector_type(4)));

__global__ __launch_bounds__(256)
void extract_diag_kernel(const float* __restrict__ w, float* __restrict__ d) {
    int i = blockIdx.x * blockDim.x + threadIdx.x;
    if (i < NCOL) {
        d[i] = w[(size_t)i * (NCOL + 1)];   // w[i*N + i], coalesced write
    }
}

__global__ __launch_bounds__(256)
void scale_bias_kernel(const f4* __restrict__ in,
                       const f4* __restrict__ diag4,
                       const f4* __restrict__ bias4,
                       f4* __restrict__ out,
                       long total4) {
    const int  t = blockIdx.x * blockDim.x + threadIdx.x;
    const int  j = t & (QCOL - 1);          // invariant: stride % QCOL == 0
    const long stride = (long)gridDim.x * blockDim.x;

    const f4 d = diag4[j];   // coalesced, L2-resident (16 KiB)
    const f4 b = bias4[j];

    // Rolled grid-stride streaming loop: 1 load + 1 store per 16 B.
    for (long i = t; i < total4; i += stride) {
        f4 x = in[i];
        f4 o;
        o.x = fmaf(x.x, d.x, b.x);
        o.y = fmaf(x.y, d.y, b.y);
        o.z = fmaf(x.z, d.z, b.z);
        o.w = fmaf(x.w, d.w, b.w);
        out[i] = o;
    }
}

extern "C" void kernel_launch(void* const* d_in, const int* in_sizes, int n_in,
                              void* d_out, int out_size, void* d_ws, size_t ws_size,
                              hipStream_t stream) {
    const float* input  = (const float*)d_in[0];
    const float* weight = (const float*)d_in[1];
    const float* bias   = (const float*)d_in[2];
    float* out  = (float*)d_out;
    float* diag = (float*)d_ws;   // 4096 floats = 16 KiB scratch

    extract_diag_kernel<<<(NCOL + 255) / 256, 256, 0, stream>>>(weight, diag);

    const long total4 = (long)NROW * NCOL / 4;  // 8,388,608 float4s
    const int block = 256;
    const int grid  = 2048;  // stride 524288, multiple of QCOL
    scale_bias_kernel<<<grid, block, 0, stream>>>(
        (const f4*)input, (const f4*)diag, (const f4*)bias, (f4*)out, total4);
}

// Round 7
// 49.404 us; speedup vs baseline: 1.0829x; 1.0829x over previous
//
#include <hip/hip_runtime.h>

// Problem: out[r][c] = in[r][c] * weight[c][c] + bias[c]
// B = 8192 rows, N = 4096 cols, all float32.
// Pure memory-bound: 128 MiB read + 128 MiB write. Copy-roofline ~43 us.
//
// Lessons:
//  - R3: nontemporal hints regressed (69.5) — bypass L2 aggregation; don't.
//  - R4: 16x unroll regressed (56.7) — long vmcnt batches kill overlap.
//  - R5: fused strided diag prologue regressed (53.1) — scattered burst.
//  - R6: hoisting diag/bias regressed vs R1 (53.5 vs 50.7) — per-iter
//    L1-hit loads were already free; hoisting gains nothing.
//  - This round: R1 body, exact-map (no grid-stride loop). One float4
//    per thread, 32768 blocks; dispatcher handles overlap; no loop
//    arithmetic, no branch.

#define NCOL 4096
#define NROW 8192
#define QCOL (NCOL / 4)   // 1024 column quads

typedef float f4 __attribute__((ext_vector_type(4)));

__global__ __launch_bounds__(256)
void extract_diag_kernel(const float* __restrict__ w, float* __restrict__ d) {
    int i = blockIdx.x * blockDim.x + threadIdx.x;
    if (i < NCOL) {
        d[i] = w[(size_t)i * (NCOL + 1)];   // w[i*N + i], coalesced write
    }
}

__global__ __launch_bounds__(256)
void scale_bias_kernel(const f4* __restrict__ in,
                       const f4* __restrict__ diag4,
                       const f4* __restrict__ bias4,
                       f4* __restrict__ out) {
    const long i = (long)blockIdx.x * blockDim.x + threadIdx.x;  // 0..2^23-1
    const int  j = (int)(i & (QCOL - 1));                        // column quad

    f4 x = in[i];
    const f4 d = diag4[j];   // L1/L2 hit (16 KiB table)
    const f4 b = bias4[j];   // L1/L2 hit
    f4 o;
    o.x = fmaf(x.x, d.x, b.x);
    o.y = fmaf(x.y, d.y, b.y);
    o.z = fmaf(x.z, d.z, b.z);
    o.w = fmaf(x.w, d.w, b.w);
    out[i] = o;
}

extern "C" void kernel_launch(void* const* d_in, const int* in_sizes, int n_in,
                              void* d_out, int out_size, void* d_ws, size_t ws_size,
                              hipStream_t stream) {
    const float* input  = (const float*)d_in[0];
    const float* weight = (const float*)d_in[1];
    const float* bias   = (const float*)d_in[2];
    float* out  = (float*)d_out;
    float* diag = (float*)d_ws;   // 4096 floats = 16 KiB scratch

    extract_diag_kernel<<<(NCOL + 255) / 256, 256, 0, stream>>>(weight, diag);

    const long total4 = (long)NROW * NCOL / 4;   // 8,388,608 float4s
    const int block = 256;
    const int grid  = (int)(total4 / block);     // 32768 blocks, exact map
    scale_bias_kernel<<<grid, block, 0, stream>>>(
        (const f4*)input, (const f4*)diag, (const f4*)bias, (f4*)out);
}

// Round 8
// 47.145 us; speedup vs baseline: 1.1348x; 1.0479x over previous
//
#include <hip/hip_runtime.h>

// Problem: out[r][c] = in[r][c] * weight[c][c] + bias[c]
// B = 8192 rows, N = 4096 cols, all float32.
// Pure memory-bound: 128 MiB read + 128 MiB write.
//
// Lessons:
//  - R3: nt on LOADS+STORES regressed (69.5) — nt loads kill L3 input
//    residency across replays (re-fetch 128 MiB from HBM every call).
//  - R4: 16x unroll regressed (56.7) — vmcnt batching kills overlap.
//  - R5/R6: strided diag prologue / hoisting: no gain over per-iter
//    L1-hit loads. R7 exact-map = 49.4 us (best).
//  - This round: R7 body + STORE-ONLY nontemporal. Replay footprint is
//    128 MiB in + 128 MiB out = 256 MiB = exactly L3 capacity; output
//    write-allocate evicts input (FETCH_SIZE showed 64 MB/replay HBM
//    re-fetch). nt stores keep output OUT of L3 -> input fully
//    L3-resident across graph replays; HBM traffic/replay -> ~128 MiB.

#define NCOL 4096
#define NROW 8192
#define QCOL (NCOL / 4)   // 1024 column quads

typedef float f4 __attribute__((ext_vector_type(4)));

__global__ __launch_bounds__(256)
void extract_diag_kernel(const float* __restrict__ w, float* __restrict__ d) {
    int i = blockIdx.x * blockDim.x + threadIdx.x;
    if (i < NCOL) {
        d[i] = w[(size_t)i * (NCOL + 1)];   // w[i*N + i], coalesced write
    }
}

__global__ __launch_bounds__(256)
void scale_bias_kernel(const f4* __restrict__ in,
                       const f4* __restrict__ diag4,
                       const f4* __restrict__ bias4,
                       f4* __restrict__ out) {
    const long i = (long)blockIdx.x * blockDim.x + threadIdx.x;  // 0..2^23-1
    const int  j = (int)(i & (QCOL - 1));                        // column quad

    f4 x = in[i];            // normal cached load (L3-resident on replays)
    const f4 d = diag4[j];   // L1/L2 hit (16 KiB table)
    const f4 b = bias4[j];   // L1/L2 hit
    f4 o;
    o.x = fmaf(x.x, d.x, b.x);
    o.y = fmaf(x.y, d.y, b.y);
    o.z = fmaf(x.z, d.z, b.z);
    o.w = fmaf(x.w, d.w, b.w);
    __builtin_nontemporal_store(o, &out[i]);   // bypass caches: don't evict input
}

extern "C" void kernel_launch(void* const* d_in, const int* in_sizes, int n_in,
                              void* d_out, int out_size, void* d_ws, size_t ws_size,
                              hipStream_t stream) {
    const float* input  = (const float*)d_in[0];
    const float* weight = (const float*)d_in[1];
    const float* bias   = (const float*)d_in[2];
    float* out  = (float*)d_out;
    float* diag = (float*)d_ws;   // 4096 floats = 16 KiB scratch

    extract_diag_kernel<<<(NCOL + 255) / 256, 256, 0, stream>>>(weight, diag);

    const long total4 = (long)NROW * NCOL / 4;   // 8,388,608 float4s
    const int block = 256;
    const int grid  = (int)(total4 / block);     // 32768 blocks, exact map
    scale_bias_kernel<<<grid, block, 0, stream>>>(
        (const f4*)input, (const f4*)diag, (const f4*)bias, (f4*)out);
}